// Round 14
// baseline (452.799 us; speedup 1.0000x reference)
//
#include <hip/hip_runtime.h>

// ---------------------------------------------------------------------------
// ActorCriticNetMixtureExpert: B=16384, D=512, H=512, HV=256, A=32, E=8, HW=512
// Outputs: actions [8,16384,32] f32 | v [16384,1] f32 | w [16384,8] f32
// ---------------------------------------------------------------------------

typedef float   f32x4 __attribute__((ext_vector_type(4)));
typedef _Float16 f16;
typedef _Float16 f16x4 __attribute__((ext_vector_type(4)));
typedef _Float16 f16x8 __attribute__((ext_vector_type(8)));

typedef __attribute__((address_space(1))) unsigned int gas_u32;
typedef __attribute__((address_space(3))) unsigned int las_u32;

__device__ __forceinline__ void gl_lds16(const void* g, void* l) {
  __builtin_amdgcn_global_load_lds((gas_u32*)g, (las_u32*)l, 16, 0, 0);
}

// bijective XCD-chunked swizzle (m204)
__device__ __forceinline__ int xcd_swz(int b, int G) {
  int q = G >> 3, r = G & 7;
  int x = b & 7, y = b >> 3;
  return (x < r ? x * (q + 1) : r * (q + 1) + (x - r) * q) + y;
}

// ---------------------------------------------------------------------------
// gemm3: 256x128 / 8 waves / BK=64, single-buffer 2-barrier. PROVEN ~731 TF.
// EPI 0: relu -> f16 out.
// EPI 4: fused value head — partial dot of relu(acc+bias) with Wv[e][col],
//        cross-lane reduce, atomicAdd into values[e][row]. No C store.
// ---------------------------------------------------------------------------
template<int EPI>
__global__ __launch_bounds__(512, 4) void gemm3_kernel(
    const f16* __restrict__ A, const f16* __restrict__ BT,
    const float* __restrict__ bias, void* __restrict__ Cv,
    const int K, const int lda, const int ldc,
    const long long sAe, const long long sCe,
    const int mT, const int nInner, const int eShift,
    const float* __restrict__ Wv, float* __restrict__ values)
{
  constexpr int BM = 256, BN = 128;
  __shared__ __align__(16) char sm[(BM + BN) * 128];
  char* Ash = sm;
  char* Bsh = sm + BM * 128;

  const int tid = threadIdx.x;
  const int lane = tid & 63;
  const int wid = tid >> 6;
  const int wr = wid >> 1, wc = wid & 1;  // 4M x 2N waves of 64x64

  const int L = xcd_swz(blockIdx.x, gridDim.x);
  const int nIn = L % nInner;
  const int m = (L / nInner) % mT;
  const int eo = L / (nInner * mT);
  const int nv0 = (eo * nInner + nIn) * BN;
  const int e = nv0 >> eShift;
  const int col0 = nv0 & ((1 << eShift) - 1);
  const int m0 = m * BM;

  const f16* Ab = A + (size_t)sAe * e + (size_t)m0 * lda;
  const f16* Bb = BT + (size_t)nv0 * K;

  f32x4 acc[4][4] = {};
  const int ksteps = K >> 6;

  for (int kt = 0; kt < ksteps; ++kt) {
    __syncthreads();  // previous iteration's LDS reads done
    const f16* Ak = Ab + (kt << 6);
    const f16* Bk = Bb + (kt << 6);
    #pragma unroll
    for (int u0 = 0; u0 < BM * 8; u0 += 512) {
      int u = u0 + tid;
      int row = u >> 3;
      int kb = ((u & 7) << 4) ^ ((row & 7) << 4);
      gl_lds16(Ak + (size_t)row * lda + (kb >> 1), Ash + u * 16);
    }
    #pragma unroll
    for (int u0 = 0; u0 < BN * 8; u0 += 512) {
      int u = u0 + tid;
      int row = u >> 3;
      int kb = ((u & 7) << 4) ^ ((row & 7) << 4);
      gl_lds16(Bk + (size_t)row * K + (kb >> 1), Bsh + u * 16);
    }
    __syncthreads();  // compiler drains vmcnt before barrier

    f16x8 af[4][2], bf[4][2];
    const int kl = (lane >> 4) << 4;
    #pragma unroll
    for (int fm = 0; fm < 4; ++fm) {
      int row = wr * 64 + fm * 16 + (lane & 15);
      int sw = (row & 7) << 4;
      af[fm][0] = *(const f16x8*)(Ash + row * 128 + (kl ^ sw));
      af[fm][1] = *(const f16x8*)(Ash + row * 128 + ((64 + kl) ^ sw));
    }
    #pragma unroll
    for (int fn = 0; fn < 4; ++fn) {
      int row = wc * 64 + fn * 16 + (lane & 15);
      int sw = (row & 7) << 4;
      bf[fn][0] = *(const f16x8*)(Bsh + row * 128 + (kl ^ sw));
      bf[fn][1] = *(const f16x8*)(Bsh + row * 128 + ((64 + kl) ^ sw));
    }
    #pragma unroll
    for (int fm = 0; fm < 4; ++fm)
      #pragma unroll
      for (int fn = 0; fn < 4; ++fn) {
        acc[fm][fn] = __builtin_amdgcn_mfma_f32_16x16x32_f16(
            bf[fn][0], af[fm][0], acc[fm][fn], 0, 0, 0);
        acc[fm][fn] = __builtin_amdgcn_mfma_f32_16x16x32_f16(
            bf[fn][1], af[fm][1], acc[fm][fn], 0, 0, 0);
      }
  }

  const int rbase = m0 + wr * 64 + (lane & 15);
  const int cb = wc * 64 + ((lane >> 4) << 2);

  if constexpr (EPI == 4) {
    #pragma unroll
    for (int fm = 0; fm < 4; ++fm) {
      const int row = rbase + fm * 16;
      float s = 0.0f;
      #pragma unroll
      for (int fn = 0; fn < 4; ++fn) {
        const int bcol = cb + fn * 16;
        const int col = col0 + bcol;
        f32x4 v = acc[fm][fn];
        f32x4 bb = *(const f32x4*)(bias + nv0 + bcol);
        #pragma unroll
        for (int r = 0; r < 4; ++r)
          s += fmaxf(v[r] + bb[r], 0.0f) * Wv[(e << 8) + col + r];
      }
      s += __shfl_xor(s, 16);
      s += __shfl_xor(s, 32);
      if (lane < 16) atomicAdd(&values[((size_t)e << 14) + row], s);
    }
    return;
  }

  #pragma unroll
  for (int fm = 0; fm < 4; ++fm) {
    const int row = rbase + fm * 16;
    #pragma unroll
    for (int fn = 0; fn < 4; ++fn) {
      const int bcol = cb + fn * 16;
      const int col = col0 + bcol;
      f32x4 v = acc[fm][fn];
      f32x4 bb = *(const f32x4*)(bias + nv0 + bcol);
      f16x4 h;
      #pragma unroll
      for (int r = 0; r < 4; ++r) h[r] = (f16)fmaxf(v[r] + bb[r], 0.0f);
      *(f16x4*)((f16*)Cv + (size_t)sCe * e + (size_t)row * ldc + col) = h;
    }
  }
}

// ---------------------------------------------------------------------------
// gemm2: 4-wave 256-thread generic tile, single-buffer 2-barrier BK=64.
// EPI 1: tanh->f32 (mu). EPI 3: relu->triple-f16 K-concat (gate L0).
// EPI 5: fused gate head — z[row][e] += sum_c relu(acc+bw1)[row][c]*Wwo[c][e]
//        (atomicAdd; no C store). Gates use <128,64,64,32> = 1024 blocks.
// ---------------------------------------------------------------------------
template<int BM, int BN, int WM, int WN, int EPI>
__global__ __launch_bounds__(256, 2) void gemm2_kernel(
    const f16* __restrict__ A, const f16* __restrict__ BT,
    const float* __restrict__ bias, void* __restrict__ Cv,
    const int K, const int lda, const int ldc,
    const long long sAe, const long long sCe,
    const int mT, const int nInner, const int eShift,
    const float* __restrict__ Wwo, float* __restrict__ zbuf)
{
  constexpr int FM = WM / 16, FN = WN / 16;
  constexpr int WAVES_N = BN / WN;
  __shared__ __align__(16) char sm[(BM + BN) * 128];
  char* Ash = sm;
  char* Bsh = sm + BM * 128;

  const int tid = threadIdx.x;
  const int lane = tid & 63;
  const int wid = tid >> 6;

  const int L = xcd_swz(blockIdx.x, gridDim.x);
  const int nIn = L % nInner;
  const int m = (L / nInner) % mT;
  const int eo = L / (nInner * mT);
  const int nv0 = (eo * nInner + nIn) * BN;
  const int e = nv0 >> eShift;
  const int col0 = nv0 & ((1 << eShift) - 1);
  const int m0 = m * BM;

  const f16* Ab = A + (size_t)sAe * e + (size_t)m0 * lda;
  const f16* Bb = BT + (size_t)nv0 * K;
  const int wr = wid / WAVES_N, wc = wid % WAVES_N;

  f32x4 acc[FM][FN] = {};
  const int ksteps = K >> 6;

  for (int kt = 0; kt < ksteps; ++kt) {
    __syncthreads();
    const f16* Ak = Ab + (kt << 6);
    const f16* Bk = Bb + (kt << 6);
    for (int u0 = 0; u0 < BM * 8; u0 += 256) {
      int u = u0 + tid;
      int row = u >> 3;
      int kb = ((u & 7) << 4) ^ ((row & 7) << 4);
      gl_lds16(Ak + (size_t)row * lda + (kb >> 1), Ash + u * 16);
    }
    for (int u0 = 0; u0 < BN * 8; u0 += 256) {
      int u = u0 + tid;
      int row = u >> 3;
      int kb = ((u & 7) << 4) ^ ((row & 7) << 4);
      gl_lds16(Bk + (size_t)row * K + (kb >> 1), Bsh + u * 16);
    }
    __syncthreads();

    f16x8 af[FM][2], bf[FN][2];
    const int kl = (lane >> 4) << 4;
    #pragma unroll
    for (int fm = 0; fm < FM; ++fm) {
      int row = wr * WM + fm * 16 + (lane & 15);
      int sw = (row & 7) << 4;
      af[fm][0] = *(const f16x8*)(Ash + row * 128 + (kl ^ sw));
      af[fm][1] = *(const f16x8*)(Ash + row * 128 + ((64 + kl) ^ sw));
    }
    #pragma unroll
    for (int fn = 0; fn < FN; ++fn) {
      int row = wc * WN + fn * 16 + (lane & 15);
      int sw = (row & 7) << 4;
      bf[fn][0] = *(const f16x8*)(Bsh + row * 128 + (kl ^ sw));
      bf[fn][1] = *(const f16x8*)(Bsh + row * 128 + ((64 + kl) ^ sw));
    }
    #pragma unroll
    for (int fm = 0; fm < FM; ++fm)
      #pragma unroll
      for (int fn = 0; fn < FN; ++fn) {
        acc[fm][fn] = __builtin_amdgcn_mfma_f32_16x16x32_f16(
            bf[fn][0], af[fm][0], acc[fm][fn], 0, 0, 0);
        acc[fm][fn] = __builtin_amdgcn_mfma_f32_16x16x32_f16(
            bf[fn][1], af[fm][1], acc[fm][fn], 0, 0, 0);
      }
  }

  const int rbase = m0 + wr * WM + (lane & 15);
  const int cb = wc * WN + ((lane >> 4) << 2);

  if constexpr (EPI == 5) {
    // fused gate head: zbuf[row][ee] += sum over this lane's cols
    #pragma unroll
    for (int fm = 0; fm < FM; ++fm) {
      const int row = rbase + fm * 16;
      float s[8] = {};
      #pragma unroll
      for (int fn = 0; fn < FN; ++fn) {
        const int bcol = cb + fn * 16;
        const int col = col0 + bcol;
        f32x4 v = acc[fm][fn];
        f32x4 bb = *(const f32x4*)(bias + nv0 + bcol);
        #pragma unroll
        for (int r = 0; r < 4; ++r) {
          float u = fmaxf(v[r] + bb[r], 0.0f);
          const float* wp = Wwo + (size_t)(col + r) * 8;
          #pragma unroll
          for (int ee = 0; ee < 8; ++ee) s[ee] += u * wp[ee];
        }
      }
      #pragma unroll
      for (int ee = 0; ee < 8; ++ee) {
        s[ee] += __shfl_xor(s[ee], 16);
        s[ee] += __shfl_xor(s[ee], 32);
      }
      if (lane < 16) {
        #pragma unroll
        for (int ee = 0; ee < 8; ++ee)
          atomicAdd(&zbuf[(size_t)row * 8 + ee], s[ee]);
      }
    }
    return;
  }

  #pragma unroll
  for (int fm = 0; fm < FM; ++fm) {
    const int row = rbase + fm * 16;
    #pragma unroll
    for (int fn = 0; fn < FN; ++fn) {
      const int bcol = cb + fn * 16;
      const int col = col0 + bcol;
      f32x4 v = acc[fm][fn];
      f32x4 bb = *(const f32x4*)(bias + nv0 + bcol);
      if constexpr (EPI == 1) {
        f32x4 o;
        #pragma unroll
        for (int r = 0; r < 4; ++r) o[r] = tanhf(v[r] + bb[r]);
        *(f32x4*)((float*)Cv + (size_t)sCe * e + (size_t)row * ldc + col) = o;
      } else {
        f16x4 h, l, s;
        #pragma unroll
        for (int r = 0; r < 4; ++r) {
          float u = fmaxf(v[r] + bb[r], 0.0f);
          f16 hh = (f16)u;
          float hv = (float)hh;
          h[r] = hh;
          l[r] = (f16)((u - hv) * 32.0f);
          s[r] = (f16)(hv * 0.03125f);
        }
        f16* cp = (f16*)Cv + (size_t)sCe * e + (size_t)row * ldc + col;
        *(f16x4*)(cp) = h;
        *(f16x4*)(cp + 512) = l;
        *(f16x4*)(cp + 1024) = s;
      }
    }
  }
}

// ---------------------------------------------------------------------------
// Fused prep: x -> triple split [B][1536] {hi, r*32, hi/32}  +  all weight
// transposes. Gate weights: triple K-concat rows {Bhi, Bhi/32, rB*32}.
// ---------------------------------------------------------------------------
__global__ __launch_bounds__(256) void prep_kernel(
    const float* __restrict__ x, f16* __restrict__ xsplit,
    const float* __restrict__ Wp0, f16* __restrict__ Wp0T,
    const float* __restrict__ Wp1, f16* __restrict__ Wp1T,
    const float* __restrict__ Wmu, f16* __restrict__ WmuT,
    const float* __restrict__ Wv0, f16* __restrict__ Wv0T,
    const float* __restrict__ Wv1, f16* __restrict__ Wv1T,
    const float* __restrict__ Ww0, f16* __restrict__ Ww0T3,
    const float* __restrict__ Ww1, f16* __restrict__ Ww1T3)
{
  __shared__ float t[32][33];
  const int tid = threadIdx.x;
  int b = blockIdx.x;
  if (b < 8192) {
    const size_t i = ((size_t)b * 256 + tid) * 4;
    const int row = (int)(i >> 9);
    const int col = (int)(i & 511);
    f32x4 v = *(const f32x4*)(x + i);
    f16x4 h, l, s;
    #pragma unroll
    for (int j = 0; j < 4; ++j) {
      f16 hh = (f16)v[j];
      float hv = (float)hh;
      h[j] = hh;
      l[j] = (f16)((v[j] - hv) * 32.0f);
      s[j] = (f16)(hv * 0.03125f);
    }
    f16* p = xsplit + (size_t)row * 1536 + col;
    *(f16x4*)(p) = h;
    *(f16x4*)(p + 512) = l;
    *(f16x4*)(p + 1024) = s;
    return;
  }
  b -= 8192;
  const float* W;
  f16* T;
  bool triple = false;
  int K, N;
  if (b < 2048)               { W = Wp0; T = Wp0T; K = 512; N = 512; }
  else if ((b -= 2048) < 2048){ W = Wp1; T = Wp1T; K = 512; N = 512; }
  else if ((b -= 2048) < 128) { W = Wmu; T = WmuT; K = 512; N = 32; }
  else if ((b -= 128) < 1024) { W = Wv0; T = Wv0T; K = 512; N = 256; }
  else if ((b -= 1024) < 512) { W = Wv1; T = Wv1T; K = 256; N = 256; }
  else if ((b -= 512) < 256)  { W = Ww0; T = Ww0T3; triple = true; K = 512; N = 512; }
  else { b -= 256;              W = Ww1; T = Ww1T3; triple = true; K = 512; N = 512; }

  const int kT = K >> 5, nT = N >> 5;
  const int e = b / (kT * nT);
  const int rem = b % (kT * nT);
  const int k0 = (rem % kT) << 5;
  const int n0 = (rem / kT) << 5;
  const int tx = tid & 31, ty = tid >> 5;
  const float* Wp = W + (size_t)e * K * N;
  #pragma unroll
  for (int i = 0; i < 4; ++i)
    t[ty + i * 8][tx] = Wp[(size_t)(k0 + ty + i * 8) * N + n0 + tx];
  __syncthreads();
  #pragma unroll
  for (int i = 0; i < 4; ++i) {
    const int n = n0 + ty + i * 8, k = k0 + tx;
    float v = t[tx][ty + i * 8];
    f16 hh = (f16)v;
    if (!triple) {
      T[(size_t)e * K * N + (size_t)n * K + k] = hh;
    } else {
      float hv = (float)hh;
      f16* p = T + (size_t)n * 1536 + k;
      p[0] = hh;
      p[512] = (f16)(hv * 0.03125f);
      p[1024] = (f16)((v - hv) * 32.0f);
    }
  }
}

// ---------------------------------------------------------------------------
// Threefry-2x32-20, key = (0, 42)
// ---------------------------------------------------------------------------
__device__ __forceinline__ void threefry_0_42(unsigned x0, unsigned x1,
                                              unsigned& o0, unsigned& o1)
{
  const unsigned ks0 = 0u, ks1 = 42u, ks2 = 0x1BD11BDAu ^ 42u;
  x0 += ks0; x1 += ks1;
#define TF_R(r) { x0 += x1; x1 = (x1 << r) | (x1 >> (32 - r)); x1 ^= x0; }
  TF_R(13) TF_R(15) TF_R(26) TF_R(6)  x0 += ks1; x1 += ks2 + 1u;
  TF_R(17) TF_R(29) TF_R(16) TF_R(24) x0 += ks2; x1 += ks0 + 2u;
  TF_R(13) TF_R(15) TF_R(26) TF_R(6)  x0 += ks0; x1 += ks1 + 3u;
  TF_R(17) TF_R(29) TF_R(16) TF_R(24) x0 += ks1; x1 += ks2 + 4u;
  TF_R(13) TF_R(15) TF_R(26) TF_R(6)  x0 += ks2; x1 += ks0 + 5u;
#undef TF_R
  o0 = x0; o1 = x1;
}

// ---------------------------------------------------------------------------
// Tail: read z[16384][8] (pre-bwo), softmax -> w, threefry gumbel categorical
// -> pis, gather v = values[pis][b] + bv[pis]. 8 lanes per row, 8 rows/wave.
// ---------------------------------------------------------------------------
__global__ __launch_bounds__(256) void tail_kernel(
    const float* __restrict__ zbuf, const float* __restrict__ bwo,
    const float* __restrict__ values, const float* __restrict__ bv,
    float* __restrict__ w_out, float* __restrict__ v_out)
{
  const int tid = threadIdx.x;
  const int lane = tid & 63, wid = tid >> 6;
  const int row = (blockIdx.x * 4 + wid) * 8 + (lane >> 3);
  const int e = lane & 7;

  float z = zbuf[(size_t)row * 8 + e] + bwo[e];

  float zm = z;
  #pragma unroll
  for (int off = 1; off < 8; off <<= 1) zm = fmaxf(zm, __shfl_xor(zm, off));
  float ew = expf(z - zm);
  float s = ew;
  #pragma unroll
  for (int off = 1; off < 8; off <<= 1) s += __shfl_xor(s, off);
  w_out[(size_t)row * 8 + e] = ew / s;

  unsigned idx = ((unsigned)row << 3) | (unsigned)e;
  unsigned o0, o1;
  threefry_0_42(0u, idx, o0, o1);
  unsigned bits = o0 ^ o1;
  float f = __uint_as_float((bits >> 9) | 0x3F800000u) - 1.0f;
  f = fmaxf(f, 1.17549435e-38f);
  float g = -logf(-logf(f));

  float my = z + g;
  int mi = e;
  #pragma unroll
  for (int off = 1; off < 8; off <<= 1) {
    float oy = __shfl_xor(my, off);
    int oi = __shfl_xor(mi, off);
    if (oy > my || (oy == my && oi < mi)) { my = oy; mi = oi; }
  }
  if (e == 0) v_out[row] = values[((size_t)mi << 14) + row] + bv[mi];
}

// ---------------------------------------------------------------------------
// host launch
// ---------------------------------------------------------------------------
extern "C" void kernel_launch(void* const* d_in, const int* in_sizes, int n_in,
                              void* d_out, int out_size, void* d_ws, size_t ws_size,
                              hipStream_t stream) {
  (void)in_sizes; (void)n_in; (void)out_size; (void)ws_size;
  const float* x   = (const float*)d_in[0];
  const float* Wp0 = (const float*)d_in[1];
  const float* bp0 = (const float*)d_in[2];
  const float* Wp1 = (const float*)d_in[3];
  const float* bp1 = (const float*)d_in[4];
  const float* Wmu = (const float*)d_in[5];
  const float* bmu = (const float*)d_in[6];
  const float* Wv0 = (const float*)d_in[7];
  const float* bv0 = (const float*)d_in[8];
  const float* Wv1 = (const float*)d_in[9];
  const float* bv1 = (const float*)d_in[10];
  const float* Wv  = (const float*)d_in[11];
  const float* bv  = (const float*)d_in[12];
  const float* Ww0 = (const float*)d_in[13];
  const float* bw0 = (const float*)d_in[14];
  const float* Ww1 = (const float*)d_in[15];
  const float* bw1 = (const float*)d_in[16];
  const float* Wwo = (const float*)d_in[17];
  const float* bwo = (const float*)d_in[18];

  float* out_actions = (float*)d_out;
  float* out_v = out_actions + (size_t)8 * 16384 * 32;
  float* out_w = out_v + 16384;

  char* base = (char*)d_ws;
  size_t off = 0;
  auto alloc = [&](size_t bytes) -> char* {
    char* p = base + off;
    off = (off + bytes + 255) & ~(size_t)255;
    return p;
  };

  f16* xsplit = (f16*)alloc((size_t)16384 * 1536 * 2);  // 48 MiB
  f16* Wp0T   = (f16*)alloc((size_t)8 * 512 * 512 * 2);
  f16* Wp1T   = (f16*)alloc((size_t)8 * 512 * 512 * 2);
  f16* WmuT   = (f16*)alloc((size_t)8 * 32 * 512 * 2);
  f16* Wv0T   = (f16*)alloc((size_t)8 * 256 * 512 * 2);
  f16* Wv1T   = (f16*)alloc((size_t)8 * 256 * 256 * 2);
  f16* Ww0T3  = (f16*)alloc((size_t)512 * 1536 * 2);
  f16* Ww1T3  = (f16*)alloc((size_t)512 * 1536 * 2);
  float* valuesBuf = (float*)alloc((size_t)8 * 16384 * 4);  // 512 KiB
  float* zbuf      = (float*)alloc((size_t)16384 * 8 * 4);  // 512 KiB (adjacent)

  // arena: P1/P2 = 64 MiB each (4-expert groups -> L3-resident intermediates)
  char* arena = base + off;
  const size_t SZ67 = (size_t)67108864;
  f16* P1 = (f16*)arena;
  f16* P2 = (f16*)(arena + SZ67);
  f16* VB1 = (f16*)arena;
  f16* U1split = (f16*)arena;                       // 48 MiB

  dim3 blk(256);
  dim3 blk8(512);
  const long long sBD = 16384LL * 512;
  const long long sBH = 16384LL * 256;

  // fused prep (cvt + all transposes); zero the two atomic accumulators
  hipMemsetAsync(valuesBuf, 0, (size_t)(8 * 16384 + 16384 * 8) * 4, stream);
  prep_kernel<<<14464, blk, 0, stream>>>(
      x, xsplit, Wp0, Wp0T, Wp1, Wp1T, Wmu, WmuT, Wv0, Wv0T, Wv1, Wv1T,
      Ww0, Ww0T3, Ww1, Ww1T3);

  // policy chain: eg=4 groups (P1/P2 L3-resident), gemm3 2-barrier
  for (int e0 = 0; e0 < 8; e0 += 4) {
    gemm3_kernel<0><<<1024, blk8, 0, stream>>>(
        xsplit, Wp0T + (size_t)e0 * 512 * 512, bp0 + e0 * 512, P1,
        512, 1536, 512, 0, sBD, 64, 16, 9, nullptr, nullptr);
    gemm3_kernel<0><<<1024, blk8, 0, stream>>>(
        P1, Wp1T + (size_t)e0 * 512 * 512, bp1 + e0 * 512, P2,
        512, 512, 512, sBD, sBD, 64, 4, 9, nullptr, nullptr);
    gemm2_kernel<128, 32, 32, 32, 1><<<512, blk, 0, stream>>>(
        P2, WmuT + (size_t)e0 * 32 * 512, bmu + e0 * 32,
        out_actions + (size_t)e0 * 16384 * 32,
        512, 512, 32, sBD, 16384LL * 32, 128, 1, 5, nullptr, nullptr);
  }

  // value chain: full 8-expert concat; L1 fused with value head (EPI 4)
  gemm3_kernel<0><<<1024, blk8, 0, stream>>>(
      xsplit, Wv0T, bv0, VB1, 512, 1536, 256, 0, sBH, 64, 16, 8,
      nullptr, nullptr);
  gemm3_kernel<4><<<1024, blk8, 0, stream>>>(
      VB1, Wv1T, bv1, nullptr, 256, 256, 256, sBH, 0, 64, 2, 8,
      Wv, valuesBuf);

  // gating: L0 triple-split (EPI 3), L1 fused with Wwo GEMV (EPI 5);
  // <128,64> tiles -> 1024 blocks (round-12 proven occupancy fix)
  gemm2_kernel<128, 64, 64, 32, 3><<<1024, blk, 0, stream>>>(
      xsplit, Ww0T3, bw0, U1split, 1536, 1536, 1536, 0, 0, 128, 8, 9,
      nullptr, nullptr);
  gemm2_kernel<128, 64, 64, 32, 5><<<1024, blk, 0, stream>>>(
      U1split, Ww1T3, bw1, nullptr, 1536, 1536, 0, 0, 0, 128, 8, 9,
      Wwo, zbuf);
  tail_kernel<<<512, blk, 0, stream>>>(zbuf, bwo, valuesBuf, bv, out_w, out_v);
}

// Round 15
// 424.964 us; speedup vs baseline: 1.0655x; 1.0655x over previous
//
#include <hip/hip_runtime.h>

// ---------------------------------------------------------------------------
// ActorCriticNetMixtureExpert: B=16384, D=512, H=512, HV=256, A=32, E=8, HW=512
// Outputs: actions [8,16384,32] f32 | v [16384,1] f32 | w [16384,8] f32
// ---------------------------------------------------------------------------

typedef float   f32x4 __attribute__((ext_vector_type(4)));
typedef _Float16 f16;
typedef _Float16 f16x4 __attribute__((ext_vector_type(4)));
typedef _Float16 f16x8 __attribute__((ext_vector_type(8)));

typedef __attribute__((address_space(1))) unsigned int gas_u32;
typedef __attribute__((address_space(3))) unsigned int las_u32;

__device__ __forceinline__ void gl_lds16(const void* g, void* l) {
  __builtin_amdgcn_global_load_lds((gas_u32*)g, (las_u32*)l, 16, 0, 0);
}

// bijective XCD-chunked swizzle (m204)
__device__ __forceinline__ int xcd_swz(int b, int G) {
  int q = G >> 3, r = G & 7;
  int x = b & 7, y = b >> 3;
  return (x < r ? x * (q + 1) : r * (q + 1) + (x - r) * q) + y;
}

// ---------------------------------------------------------------------------
// gemm3: 256x128 / 8 waves / BK=64, single-buffer 2-barrier. PROVEN ~731 TF.
// EPI 0: relu -> f16 out.
// EPI 4: fused value head — partial dot of relu(acc+bias) with Wv[e][col],
//        cross-lane reduce, atomicAdd into values[e][row]. No C store.
//        (2-way contention, 524K atomics: measured -37us. The 8-way/2M-atomic
//         EPI-5 gate variant inverted to +48us — fusion boundary measured.)
// ---------------------------------------------------------------------------
template<int EPI>
__global__ __launch_bounds__(512, 4) void gemm3_kernel(
    const f16* __restrict__ A, const f16* __restrict__ BT,
    const float* __restrict__ bias, void* __restrict__ Cv,
    const int K, const int lda, const int ldc,
    const long long sAe, const long long sCe,
    const int mT, const int nInner, const int eShift,
    const float* __restrict__ Wv, float* __restrict__ values)
{
  constexpr int BM = 256, BN = 128;
  __shared__ __align__(16) char sm[(BM + BN) * 128];
  char* Ash = sm;
  char* Bsh = sm + BM * 128;

  const int tid = threadIdx.x;
  const int lane = tid & 63;
  const int wid = tid >> 6;
  const int wr = wid >> 1, wc = wid & 1;  // 4M x 2N waves of 64x64

  const int L = xcd_swz(blockIdx.x, gridDim.x);
  const int nIn = L % nInner;
  const int m = (L / nInner) % mT;
  const int eo = L / (nInner * mT);
  const int nv0 = (eo * nInner + nIn) * BN;
  const int e = nv0 >> eShift;
  const int col0 = nv0 & ((1 << eShift) - 1);
  const int m0 = m * BM;

  const f16* Ab = A + (size_t)sAe * e + (size_t)m0 * lda;
  const f16* Bb = BT + (size_t)nv0 * K;

  f32x4 acc[4][4] = {};
  const int ksteps = K >> 6;

  for (int kt = 0; kt < ksteps; ++kt) {
    __syncthreads();  // previous iteration's LDS reads done
    const f16* Ak = Ab + (kt << 6);
    const f16* Bk = Bb + (kt << 6);
    #pragma unroll
    for (int u0 = 0; u0 < BM * 8; u0 += 512) {
      int u = u0 + tid;
      int row = u >> 3;
      int kb = ((u & 7) << 4) ^ ((row & 7) << 4);
      gl_lds16(Ak + (size_t)row * lda + (kb >> 1), Ash + u * 16);
    }
    #pragma unroll
    for (int u0 = 0; u0 < BN * 8; u0 += 512) {
      int u = u0 + tid;
      int row = u >> 3;
      int kb = ((u & 7) << 4) ^ ((row & 7) << 4);
      gl_lds16(Bk + (size_t)row * K + (kb >> 1), Bsh + u * 16);
    }
    __syncthreads();  // compiler drains vmcnt before barrier

    f16x8 af[4][2], bf[4][2];
    const int kl = (lane >> 4) << 4;
    #pragma unroll
    for (int fm = 0; fm < 4; ++fm) {
      int row = wr * 64 + fm * 16 + (lane & 15);
      int sw = (row & 7) << 4;
      af[fm][0] = *(const f16x8*)(Ash + row * 128 + (kl ^ sw));
      af[fm][1] = *(const f16x8*)(Ash + row * 128 + ((64 + kl) ^ sw));
    }
    #pragma unroll
    for (int fn = 0; fn < 4; ++fn) {
      int row = wc * 64 + fn * 16 + (lane & 15);
      int sw = (row & 7) << 4;
      bf[fn][0] = *(const f16x8*)(Bsh + row * 128 + (kl ^ sw));
      bf[fn][1] = *(const f16x8*)(Bsh + row * 128 + ((64 + kl) ^ sw));
    }
    #pragma unroll
    for (int fm = 0; fm < 4; ++fm)
      #pragma unroll
      for (int fn = 0; fn < 4; ++fn) {
        acc[fm][fn] = __builtin_amdgcn_mfma_f32_16x16x32_f16(
            bf[fn][0], af[fm][0], acc[fm][fn], 0, 0, 0);
        acc[fm][fn] = __builtin_amdgcn_mfma_f32_16x16x32_f16(
            bf[fn][1], af[fm][1], acc[fm][fn], 0, 0, 0);
      }
  }

  const int rbase = m0 + wr * 64 + (lane & 15);
  const int cb = wc * 64 + ((lane >> 4) << 2);

  if constexpr (EPI == 4) {
    #pragma unroll
    for (int fm = 0; fm < 4; ++fm) {
      const int row = rbase + fm * 16;
      float s = 0.0f;
      #pragma unroll
      for (int fn = 0; fn < 4; ++fn) {
        const int bcol = cb + fn * 16;
        const int col = col0 + bcol;
        f32x4 v = acc[fm][fn];
        f32x4 bb = *(const f32x4*)(bias + nv0 + bcol);
        #pragma unroll
        for (int r = 0; r < 4; ++r)
          s += fmaxf(v[r] + bb[r], 0.0f) * Wv[(e << 8) + col + r];
      }
      s += __shfl_xor(s, 16);
      s += __shfl_xor(s, 32);
      if (lane < 16) atomicAdd(&values[((size_t)e << 14) + row], s);
    }
    return;
  }

  #pragma unroll
  for (int fm = 0; fm < 4; ++fm) {
    const int row = rbase + fm * 16;
    #pragma unroll
    for (int fn = 0; fn < 4; ++fn) {
      const int bcol = cb + fn * 16;
      const int col = col0 + bcol;
      f32x4 v = acc[fm][fn];
      f32x4 bb = *(const f32x4*)(bias + nv0 + bcol);
      f16x4 h;
      #pragma unroll
      for (int r = 0; r < 4; ++r) h[r] = (f16)fmaxf(v[r] + bb[r], 0.0f);
      *(f16x4*)((f16*)Cv + (size_t)sCe * e + (size_t)row * ldc + col) = h;
    }
  }
}

// ---------------------------------------------------------------------------
// gemm2: 4-wave 256-thread generic tile, single-buffer 2-barrier BK=64.
// EPI 1: tanh->f32 (mu). EPI 2: relu->f32. EPI 3: relu->triple-f16 K-concat.
// Gates use <128,128,64,64> (round-11/13 best-measured config).
// ---------------------------------------------------------------------------
template<int BM, int BN, int WM, int WN, int EPI>
__global__ __launch_bounds__(256, 2) void gemm2_kernel(
    const f16* __restrict__ A, const f16* __restrict__ BT,
    const float* __restrict__ bias, void* __restrict__ Cv,
    const int K, const int lda, const int ldc,
    const long long sAe, const long long sCe,
    const int mT, const int nInner, const int eShift)
{
  constexpr int FM = WM / 16, FN = WN / 16;
  constexpr int WAVES_N = BN / WN;
  __shared__ __align__(16) char sm[(BM + BN) * 128];
  char* Ash = sm;
  char* Bsh = sm + BM * 128;

  const int tid = threadIdx.x;
  const int lane = tid & 63;
  const int wid = tid >> 6;

  const int L = xcd_swz(blockIdx.x, gridDim.x);
  const int nIn = L % nInner;
  const int m = (L / nInner) % mT;
  const int eo = L / (nInner * mT);
  const int nv0 = (eo * nInner + nIn) * BN;
  const int e = nv0 >> eShift;
  const int col0 = nv0 & ((1 << eShift) - 1);
  const int m0 = m * BM;

  const f16* Ab = A + (size_t)sAe * e + (size_t)m0 * lda;
  const f16* Bb = BT + (size_t)nv0 * K;
  const int wr = wid / WAVES_N, wc = wid % WAVES_N;

  f32x4 acc[FM][FN] = {};
  const int ksteps = K >> 6;

  for (int kt = 0; kt < ksteps; ++kt) {
    __syncthreads();
    const f16* Ak = Ab + (kt << 6);
    const f16* Bk = Bb + (kt << 6);
    for (int u0 = 0; u0 < BM * 8; u0 += 256) {
      int u = u0 + tid;
      int row = u >> 3;
      int kb = ((u & 7) << 4) ^ ((row & 7) << 4);
      gl_lds16(Ak + (size_t)row * lda + (kb >> 1), Ash + u * 16);
    }
    for (int u0 = 0; u0 < BN * 8; u0 += 256) {
      int u = u0 + tid;
      int row = u >> 3;
      int kb = ((u & 7) << 4) ^ ((row & 7) << 4);
      gl_lds16(Bk + (size_t)row * K + (kb >> 1), Bsh + u * 16);
    }
    __syncthreads();

    f16x8 af[FM][2], bf[FN][2];
    const int kl = (lane >> 4) << 4;
    #pragma unroll
    for (int fm = 0; fm < FM; ++fm) {
      int row = wr * WM + fm * 16 + (lane & 15);
      int sw = (row & 7) << 4;
      af[fm][0] = *(const f16x8*)(Ash + row * 128 + (kl ^ sw));
      af[fm][1] = *(const f16x8*)(Ash + row * 128 + ((64 + kl) ^ sw));
    }
    #pragma unroll
    for (int fn = 0; fn < FN; ++fn) {
      int row = wc * WN + fn * 16 + (lane & 15);
      int sw = (row & 7) << 4;
      bf[fn][0] = *(const f16x8*)(Bsh + row * 128 + (kl ^ sw));
      bf[fn][1] = *(const f16x8*)(Bsh + row * 128 + ((64 + kl) ^ sw));
    }
    #pragma unroll
    for (int fm = 0; fm < FM; ++fm)
      #pragma unroll
      for (int fn = 0; fn < FN; ++fn) {
        acc[fm][fn] = __builtin_amdgcn_mfma_f32_16x16x32_f16(
            bf[fn][0], af[fm][0], acc[fm][fn], 0, 0, 0);
        acc[fm][fn] = __builtin_amdgcn_mfma_f32_16x16x32_f16(
            bf[fn][1], af[fm][1], acc[fm][fn], 0, 0, 0);
      }
  }

  const int rbase = m0 + wr * WM + (lane & 15);
  const int cb = wc * WN + ((lane >> 4) << 2);
  #pragma unroll
  for (int fm = 0; fm < FM; ++fm) {
    const int row = rbase + fm * 16;
    #pragma unroll
    for (int fn = 0; fn < FN; ++fn) {
      const int bcol = cb + fn * 16;
      const int col = col0 + bcol;
      f32x4 v = acc[fm][fn];
      f32x4 bb = *(const f32x4*)(bias + nv0 + bcol);
      if constexpr (EPI == 1) {
        f32x4 o;
        #pragma unroll
        for (int r = 0; r < 4; ++r) o[r] = tanhf(v[r] + bb[r]);
        *(f32x4*)((float*)Cv + (size_t)sCe * e + (size_t)row * ldc + col) = o;
      } else if constexpr (EPI == 2) {
        f32x4 o;
        #pragma unroll
        for (int r = 0; r < 4; ++r) o[r] = fmaxf(v[r] + bb[r], 0.0f);
        *(f32x4*)((float*)Cv + (size_t)sCe * e + (size_t)row * ldc + col) = o;
      } else {
        f16x4 h, l, s;
        #pragma unroll
        for (int r = 0; r < 4; ++r) {
          float u = fmaxf(v[r] + bb[r], 0.0f);
          f16 hh = (f16)u;
          float hv = (float)hh;
          h[r] = hh;
          l[r] = (f16)((u - hv) * 32.0f);
          s[r] = (f16)(hv * 0.03125f);
        }
        f16* cp = (f16*)Cv + (size_t)sCe * e + (size_t)row * ldc + col;
        *(f16x4*)(cp) = h;
        *(f16x4*)(cp + 512) = l;
        *(f16x4*)(cp + 1024) = s;
      }
    }
  }
}

// ---------------------------------------------------------------------------
// Fused prep: x -> triple split [B][1536] {hi, r*32, hi/32}  +  all weight
// transposes. Gate weights: triple K-concat rows {Bhi, Bhi/32, rB*32}.
// ---------------------------------------------------------------------------
__global__ __launch_bounds__(256) void prep_kernel(
    const float* __restrict__ x, f16* __restrict__ xsplit,
    const float* __restrict__ Wp0, f16* __restrict__ Wp0T,
    const float* __restrict__ Wp1, f16* __restrict__ Wp1T,
    const float* __restrict__ Wmu, f16* __restrict__ WmuT,
    const float* __restrict__ Wv0, f16* __restrict__ Wv0T,
    const float* __restrict__ Wv1, f16* __restrict__ Wv1T,
    const float* __restrict__ Ww0, f16* __restrict__ Ww0T3,
    const float* __restrict__ Ww1, f16* __restrict__ Ww1T3)
{
  __shared__ float t[32][33];
  const int tid = threadIdx.x;
  int b = blockIdx.x;
  if (b < 8192) {
    const size_t i = ((size_t)b * 256 + tid) * 4;
    const int row = (int)(i >> 9);
    const int col = (int)(i & 511);
    f32x4 v = *(const f32x4*)(x + i);
    f16x4 h, l, s;
    #pragma unroll
    for (int j = 0; j < 4; ++j) {
      f16 hh = (f16)v[j];
      float hv = (float)hh;
      h[j] = hh;
      l[j] = (f16)((v[j] - hv) * 32.0f);
      s[j] = (f16)(hv * 0.03125f);
    }
    f16* p = xsplit + (size_t)row * 1536 + col;
    *(f16x4*)(p) = h;
    *(f16x4*)(p + 512) = l;
    *(f16x4*)(p + 1024) = s;
    return;
  }
  b -= 8192;
  const float* W;
  f16* T;
  bool triple = false;
  int K, N;
  if (b < 2048)               { W = Wp0; T = Wp0T; K = 512; N = 512; }
  else if ((b -= 2048) < 2048){ W = Wp1; T = Wp1T; K = 512; N = 512; }
  else if ((b -= 2048) < 128) { W = Wmu; T = WmuT; K = 512; N = 32; }
  else if ((b -= 128) < 1024) { W = Wv0; T = Wv0T; K = 512; N = 256; }
  else if ((b -= 1024) < 512) { W = Wv1; T = Wv1T; K = 256; N = 256; }
  else if ((b -= 512) < 256)  { W = Ww0; T = Ww0T3; triple = true; K = 512; N = 512; }
  else { b -= 256;              W = Ww1; T = Ww1T3; triple = true; K = 512; N = 512; }

  const int kT = K >> 5, nT = N >> 5;
  const int e = b / (kT * nT);
  const int rem = b % (kT * nT);
  const int k0 = (rem % kT) << 5;
  const int n0 = (rem / kT) << 5;
  const int tx = tid & 31, ty = tid >> 5;
  const float* Wp = W + (size_t)e * K * N;
  #pragma unroll
  for (int i = 0; i < 4; ++i)
    t[ty + i * 8][tx] = Wp[(size_t)(k0 + ty + i * 8) * N + n0 + tx];
  __syncthreads();
  #pragma unroll
  for (int i = 0; i < 4; ++i) {
    const int n = n0 + ty + i * 8, k = k0 + tx;
    float v = t[tx][ty + i * 8];
    f16 hh = (f16)v;
    if (!triple) {
      T[(size_t)e * K * N + (size_t)n * K + k] = hh;
    } else {
      float hv = (float)hh;
      f16* p = T + (size_t)n * 1536 + k;
      p[0] = hh;
      p[512] = (f16)(hv * 0.03125f);
      p[1024] = (f16)((v - hv) * 32.0f);
    }
  }
}

// ---------------------------------------------------------------------------
// Threefry-2x32-20, key = (0, 42)
// ---------------------------------------------------------------------------
__device__ __forceinline__ void threefry_0_42(unsigned x0, unsigned x1,
                                              unsigned& o0, unsigned& o1)
{
  const unsigned ks0 = 0u, ks1 = 42u, ks2 = 0x1BD11BDAu ^ 42u;
  x0 += ks0; x1 += ks1;
#define TF_R(r) { x0 += x1; x1 = (x1 << r) | (x1 >> (32 - r)); x1 ^= x0; }
  TF_R(13) TF_R(15) TF_R(26) TF_R(6)  x0 += ks1; x1 += ks2 + 1u;
  TF_R(17) TF_R(29) TF_R(16) TF_R(24) x0 += ks2; x1 += ks0 + 2u;
  TF_R(13) TF_R(15) TF_R(26) TF_R(6)  x0 += ks0; x1 += ks1 + 3u;
  TF_R(17) TF_R(29) TF_R(16) TF_R(24) x0 += ks1; x1 += ks2 + 4u;
  TF_R(13) TF_R(15) TF_R(26) TF_R(6)  x0 += ks2; x1 += ks0 + 5u;
#undef TF_R
  o0 = x0; o1 = x1;
}

// ---------------------------------------------------------------------------
// Gating tail (GEMV + softmax + partitionable-threefry categorical + gather).
// values holds the fused dot (no bv); bv added at gather.
// ---------------------------------------------------------------------------
__global__ __launch_bounds__(256) void gating_out_kernel(
    const float* __restrict__ U2, const float* __restrict__ Wwo,
    const float* __restrict__ bwo, const float* __restrict__ values,
    const float* __restrict__ bv,
    float* __restrict__ w_out, float* __restrict__ v_out)
{
  __shared__ float wl[4096];
  const int tid = threadIdx.x;
  for (int i = tid; i < 1024; i += 256)
    ((f32x4*)wl)[i] = ((const f32x4*)Wwo)[i];
  __syncthreads();
  const int lane = tid & 63, wid = tid >> 6;
  const int b = blockIdx.x * 4 + wid;

  const float* u = U2 + (size_t)b * 512 + lane * 8;
  f32x4 ua = *(const f32x4*)u;
  f32x4 ub = *(const f32x4*)(u + 4);
  float acc[8] = {};
  const float* wrow = wl + lane * 64;
  #pragma unroll
  for (int i = 0; i < 8; ++i) {
    float uv = (i < 4) ? ua[i] : ub[i - 4];
    #pragma unroll
    for (int ee = 0; ee < 8; ++ee) acc[ee] += uv * wrow[i * 8 + ee];
  }
  #pragma unroll
  for (int off = 32; off >= 1; off >>= 1)
    #pragma unroll
    for (int ee = 0; ee < 8; ++ee) acc[ee] += __shfl_xor(acc[ee], off);
  #pragma unroll
  for (int ee = 0; ee < 8; ++ee) acc[ee] += bwo[ee];

  float zmax = acc[0];
  #pragma unroll
  for (int ee = 1; ee < 8; ++ee) zmax = fmaxf(zmax, acc[ee]);
  float s = 0.0f;
  #pragma unroll
  for (int ee = 0; ee < 8; ++ee) s += expf(acc[ee] - zmax);

  float t0 = (lane & 1) ? acc[1] : acc[0];
  float t1 = (lane & 1) ? acc[3] : acc[2];
  float t2 = (lane & 1) ? acc[5] : acc[4];
  float t3 = (lane & 1) ? acc[7] : acc[6];
  float s0 = (lane & 2) ? t1 : t0;
  float s1 = (lane & 2) ? t3 : t2;
  float zown = (lane & 4) ? s1 : s0;

  if (lane < 8) w_out[(size_t)b * 8 + lane] = expf(zown - zmax) / s;

  unsigned idx = ((unsigned)b << 3) | (unsigned)(lane & 7);
  unsigned o0, o1;
  threefry_0_42(0u, idx, o0, o1);
  unsigned bits = o0 ^ o1;
  float f = __uint_as_float((bits >> 9) | 0x3F800000u) - 1.0f;
  f = fmaxf(f, 1.17549435e-38f);
  float g = -logf(-logf(f));
  float y = (lane < 8) ? (zown + g) : -3.0e38f;

  float best = __shfl(y, 0);
  int pi = 0;
  #pragma unroll
  for (int ee = 1; ee < 8; ++ee) {
    float ye = __shfl(y, ee);
    if (ye > best) { best = ye; pi = ee; }
  }
  if (lane == 0) v_out[b] = values[((size_t)pi << 14) + b] + bv[pi];
}

// ---------------------------------------------------------------------------
// host launch
// ---------------------------------------------------------------------------
extern "C" void kernel_launch(void* const* d_in, const int* in_sizes, int n_in,
                              void* d_out, int out_size, void* d_ws, size_t ws_size,
                              hipStream_t stream) {
  (void)in_sizes; (void)n_in; (void)out_size; (void)ws_size;
  const float* x   = (const float*)d_in[0];
  const float* Wp0 = (const float*)d_in[1];
  const float* bp0 = (const float*)d_in[2];
  const float* Wp1 = (const float*)d_in[3];
  const float* bp1 = (const float*)d_in[4];
  const float* Wmu = (const float*)d_in[5];
  const float* bmu = (const float*)d_in[6];
  const float* Wv0 = (const float*)d_in[7];
  const float* bv0 = (const float*)d_in[8];
  const float* Wv1 = (const float*)d_in[9];
  const float* bv1 = (const float*)d_in[10];
  const float* Wv  = (const float*)d_in[11];
  const float* bv  = (const float*)d_in[12];
  const float* Ww0 = (const float*)d_in[13];
  const float* bw0 = (const float*)d_in[14];
  const float* Ww1 = (const float*)d_in[15];
  const float* bw1 = (const float*)d_in[16];
  const float* Wwo = (const float*)d_in[17];
  const float* bwo = (const float*)d_in[18];

  float* out_actions = (float*)d_out;
  float* out_v = out_actions + (size_t)8 * 16384 * 32;
  float* out_w = out_v + 16384;

  char* base = (char*)d_ws;
  size_t off = 0;
  auto alloc = [&](size_t bytes) -> char* {
    char* p = base + off;
    off = (off + bytes + 255) & ~(size_t)255;
    return p;
  };

  f16* xsplit = (f16*)alloc((size_t)16384 * 1536 * 2);  // 48 MiB
  f16* Wp0T   = (f16*)alloc((size_t)8 * 512 * 512 * 2);
  f16* Wp1T   = (f16*)alloc((size_t)8 * 512 * 512 * 2);
  f16* WmuT   = (f16*)alloc((size_t)8 * 32 * 512 * 2);
  f16* Wv0T   = (f16*)alloc((size_t)8 * 256 * 512 * 2);
  f16* Wv1T   = (f16*)alloc((size_t)8 * 256 * 256 * 2);
  f16* Ww0T3  = (f16*)alloc((size_t)512 * 1536 * 2);
  f16* Ww1T3  = (f16*)alloc((size_t)512 * 1536 * 2);
  float* valuesBuf = (float*)alloc((size_t)8 * 16384 * 4);

  // arena: P1/P2 = 64 MiB each (4-expert groups -> L3-resident intermediates)
  char* arena = base + off;
  const size_t SZ67 = (size_t)67108864;
  f16* P1 = (f16*)arena;
  f16* P2 = (f16*)(arena + SZ67);
  f16* VB1 = (f16*)arena;
  f16* U1split = (f16*)arena;                       // 48 MiB
  float* U2 = (float*)(arena + (size_t)50331648);   // 32 MiB

  dim3 blk(256);
  dim3 blk8(512);
  const long long sBD = 16384LL * 512;
  const long long sBH = 16384LL * 256;

  // fused prep (cvt + all transposes)
  prep_kernel<<<14464, blk, 0, stream>>>(
      x, xsplit, Wp0, Wp0T, Wp1, Wp1T, Wmu, WmuT, Wv0, Wv0T, Wv1, Wv1T,
      Ww0, Ww0T3, Ww1, Ww1T3);

  // policy chain: eg=4 groups (P1/P2 L3-resident), gemm3 2-barrier
  for (int e0 = 0; e0 < 8; e0 += 4) {
    gemm3_kernel<0><<<1024, blk8, 0, stream>>>(
        xsplit, Wp0T + (size_t)e0 * 512 * 512, bp0 + e0 * 512, P1,
        512, 1536, 512, 0, sBD, 64, 16, 9, nullptr, nullptr);
    gemm3_kernel<0><<<1024, blk8, 0, stream>>>(
        P1, Wp1T + (size_t)e0 * 512 * 512, bp1 + e0 * 512, P2,
        512, 512, 512, sBD, sBD, 64, 4, 9, nullptr, nullptr);
    gemm2_kernel<128, 32, 32, 32, 1><<<512, blk, 0, stream>>>(
        P2, WmuT + (size_t)e0 * 32 * 512, bmu + e0 * 32,
        out_actions + (size_t)e0 * 16384 * 32,
        512, 512, 32, sBD, 16384LL * 32, 128, 1, 5);
  }

  // value chain: full 8-expert concat; L1 fused with value head (EPI 4)
  gemm3_kernel<0><<<1024, blk8, 0, stream>>>(
      xsplit, Wv0T, bv0, VB1, 512, 1536, 256, 0, sBH, 64, 16, 8,
      nullptr, nullptr);
  hipMemsetAsync(valuesBuf, 0, (size_t)8 * 16384 * 4, stream);
  gemm3_kernel<4><<<1024, blk8, 0, stream>>>(
      VB1, Wv1T, bv1, nullptr, 256, 256, 256, sBH, 0, 64, 2, 8,
      Wv, valuesBuf);

  // gating: two high-precision GEMMs via K-concat triple split (K=1536),
  // on 128x128 tiles -> 512 blocks (round-11/13 best config)
  gemm2_kernel<128, 128, 64, 64, 3><<<512, blk, 0, stream>>>(
      xsplit, Ww0T3, bw0, U1split, 1536, 1536, 1536, 0, 0, 128, 4, 9);
  gemm2_kernel<128, 128, 64, 64, 2><<<512, blk, 0, stream>>>(
      U1split, Ww1T3, bw1, U2, 1536, 1536, 512, 0, 0, 128, 4, 9);
  gating_out_kernel<<<4096, blk, 0, stream>>>(
      U2, Wwo, bwo, valuesBuf, bv, out_w, out_v);
}